// Round 1
// baseline (214.227 us; speedup 1.0000x reference)
//
#include <hip/hip_runtime.h>

// Causal flash attention, B=4 H=16 S=2048 D=64, fp32 in/out, bf16 MFMA.
// R2: pre-convert K/V to bf16 swizzled tile images in d_ws (pre-pass kernel),
// main kernel stages via global_load_lds width=16 (no VALU conversion),
// double-buffered K/V (1 barrier/tile), no-running-max softmax with row sums
// via ones-MFMA, heavy-first block order. Fallback (in-kernel convert) if
// ws_size < 32 MB.
// R3: XCD-affinity blockIdx swizzle — each XCD owns 8 bh (4 MiB KV working
// set == per-XCD L2), so the ~540 MB of K/V tile re-reads hit L2 instead of
// thrashing to LLC/HBM. bx&7 = XCD (2048 blocks, 2048%8==0, bijective).

#define S_LEN 2048
#define D_HEAD 64
#define NBH 64      // B*H
#define QBLK 32     // S / 64
#define TILE_E 4096 // 64x64 elements per k-tile image

typedef float f32x4 __attribute__((ext_vector_type(4)));
typedef short s16x8 __attribute__((ext_vector_type(8)));

#define SCLOG2E (0.125f * 1.44269504088896340736f)  // 1/sqrt(D) * log2(e)

__device__ __forceinline__ unsigned short f2bf(float x) {  // RNE (pre-pass)
    union { float f; unsigned int u; } v; v.f = x;
    unsigned int u = v.u + 0x7FFFu + ((v.u >> 16) & 1u);
    return (unsigned short)(u >> 16);
}
__device__ __forceinline__ unsigned short f2bf_hu(float x) { // half-up (P path)
    union { float f; unsigned int u; } v; v.f = x;
    return (unsigned short)((v.u + 0x8000u) >> 16);
}

// chunk-rotation swizzle (R1-verified: 0 bank conflicts)
__device__ __forceinline__ int swz(int row, int col) {
    return row * 64 + ((((col >> 3) + row) & 7) << 3) + (col & 7);
}

// async global->LDS, 16B per lane; lds dst must be wave-uniform base (lane*16 auto)
__device__ __forceinline__ void g2l(const unsigned short* g, unsigned short* l) {
    __builtin_amdgcn_global_load_lds(
        (const __attribute__((address_space(1))) void*)g,
        (__attribute__((address_space(3))) void*)l, 16, 0, 0);
}

// ---------- pre-pass: fp32 K,V -> bf16 swizzled tile images in workspace ----
__global__ __launch_bounds__(256)
void preconv_kernel(const float* __restrict__ K, const float* __restrict__ V,
                    unsigned short* __restrict__ Kw, unsigned short* __restrict__ Vw)
{
    __shared__ __align__(16) unsigned short kt[TILE_E];
    __shared__ __align__(16) unsigned short vt[TILE_E];
    const int bh = blockIdx.x & (NBH - 1);
    const int j  = blockIdx.x >> 6;
    const float* k = K + (size_t)bh * (S_LEN * D_HEAD) + (size_t)j * 64 * D_HEAD;
    const float* v = V + (size_t)bh * (S_LEN * D_HEAD) + (size_t)j * 64 * D_HEAD;
    const int t = threadIdx.x;

    // K tile, row-major [key][d], swizzled
#pragma unroll
    for (int i = 0; i < 2; ++i) {
        int chunk = t + 256 * i;
        int row = chunk >> 3, c = chunk & 7;
        const float* p = k + (size_t)row * D_HEAD + c * 8;
        float4 x = *(const float4*)p;
        float4 y = *(const float4*)(p + 4);
        s16x8 f;
        f[0] = (short)f2bf(x.x); f[1] = (short)f2bf(x.y);
        f[2] = (short)f2bf(x.z); f[3] = (short)f2bf(x.w);
        f[4] = (short)f2bf(y.x); f[5] = (short)f2bf(y.y);
        f[6] = (short)f2bf(y.z); f[7] = (short)f2bf(y.w);
        *(s16x8*)&kt[swz(row, c * 8)] = f;
    }
    // V tile, transposed [d][key], swizzled
    {
        int key = t & 63, cc = t >> 6;
#pragma unroll
        for (int ci = 0; ci < 2; ++ci) {
            int c = cc + ci * 4;
            const float* p = v + (size_t)key * D_HEAD + c * 8;
            float4 x = *(const float4*)p;
            float4 y = *(const float4*)(p + 4);
            float vals[8] = {x.x, x.y, x.z, x.w, y.x, y.y, y.z, y.w};
#pragma unroll
            for (int jj = 0; jj < 8; ++jj)
                vt[swz(c * 8 + jj, key)] = f2bf(vals[jj]);
        }
    }
    __syncthreads();
    // dump LDS images verbatim, coalesced
    const size_t tb = (size_t)(bh * QBLK + j) * TILE_E;
#pragma unroll
    for (int i = 0; i < 2; ++i) {
        int idx = (t + 256 * i) * 8;
        *(s16x8*)&Kw[tb + idx] = *(const s16x8*)&kt[idx];
        *(s16x8*)&Vw[tb + idx] = *(const s16x8*)&vt[idx];
    }
}

// ---------------------------- main kernel -----------------------------------
template <bool PRE>
__global__ __launch_bounds__(256, 2)
void fattn_kernel(const float* __restrict__ Qg, const float* __restrict__ Kg,
                  const float* __restrict__ Vg, float* __restrict__ Og,
                  const unsigned short* __restrict__ Kw,
                  const unsigned short* __restrict__ Vw)
{
    __shared__ __align__(16) unsigned short ks[2][TILE_E];
    __shared__ __align__(16) unsigned short vs[2][TILE_E];
    __shared__ __align__(16) unsigned short ps[4][1024];

    // XCD-affinity decode: raw dispatch round-robins bx over the 8 XCDs, so
    // bx&7 == XCD id (grid 2048 % 8 == 0). Give each XCD 8 bh -> its KV
    // working set (8 x 512 KB) exactly fills the 4 MiB per-XCD L2.
    // qb heavy-first is preserved: low bx -> qb = 31.
    const int bx   = blockIdx.x;
    const int xcd  = bx & 7;
    const int slot = bx >> 3;                    // 0..255 per XCD
    const int bh   = xcd + ((slot & 7) << 3);    // 8 bh per XCD
    const int qb   = (QBLK - 1) - (slot >> 3);   // heavy blocks first
    const size_t base = (size_t)bh * (S_LEN * D_HEAD);
    const float* q = Qg + base;
    const float* k = Kg + base;
    const float* v = Vg + base;
    float*       o = Og + base;

    const int t    = threadIdx.x;
    const int w    = t >> 6;
    const int lane = t & 63;
    const int col  = lane & 15;
    const int quad = lane >> 4;

    // Q fragments (A-layout), fp32->bf16 once per block
    s16x8 qa[2];
    {
        const int qr = qb * 64 + w * 16 + col;
        const float* p0 = q + (size_t)qr * D_HEAD + quad * 8;
#pragma unroll
        for (int kt2 = 0; kt2 < 2; ++kt2) {
            const float* p = p0 + kt2 * 32;
            float4 x = *(const float4*)(p);
            float4 y = *(const float4*)(p + 4);
            s16x8 f;
            f[0] = (short)f2bf(x.x); f[1] = (short)f2bf(x.y);
            f[2] = (short)f2bf(x.z); f[3] = (short)f2bf(x.w);
            f[4] = (short)f2bf(y.x); f[5] = (short)f2bf(y.y);
            f[6] = (short)f2bf(y.z); f[7] = (short)f2bf(y.w);
            qa[kt2] = f;
        }
    }

    s16x8 ones;
#pragma unroll
    for (int i = 0; i < 8; ++i) ones[i] = (short)0x3F80;  // bf16 1.0

    f32x4 oacc[4], lf;
#pragma unroll
    for (int nt = 0; nt < 4; ++nt) oacc[nt] = (f32x4){0.f, 0.f, 0.f, 0.f};
    lf = (f32x4){0.f, 0.f, 0.f, 0.f};

    auto stage = [&](int jt, int buf) {
        if constexpr (PRE) {
            const size_t tb = (size_t)(bh * QBLK + jt) * TILE_E;
#pragma unroll
            for (int i = 0; i < 2; ++i) {
                int c = w * 2 + i;             // 8 chunks of 512 elem (1 KiB)
                g2l(Kw + tb + c * 512 + lane * 8, &ks[buf][c * 512]);
                g2l(Vw + tb + c * 512 + lane * 8, &vs[buf][c * 512]);
            }
        } else {
            const int kb = jt * 64;
#pragma unroll
            for (int i = 0; i < 2; ++i) {
                int chunk = t + 256 * i;
                int row = chunk >> 3, c = chunk & 7;
                const float* p = k + (size_t)(kb + row) * D_HEAD + c * 8;
                float4 x = *(const float4*)p;
                float4 y = *(const float4*)(p + 4);
                s16x8 f;
                f[0] = (short)f2bf(x.x); f[1] = (short)f2bf(x.y);
                f[2] = (short)f2bf(x.z); f[3] = (short)f2bf(x.w);
                f[4] = (short)f2bf(y.x); f[5] = (short)f2bf(y.y);
                f[6] = (short)f2bf(y.z); f[7] = (short)f2bf(y.w);
                *(s16x8*)&ks[buf][swz(row, c * 8)] = f;
            }
            int key = t & 63, cc = t >> 6;
#pragma unroll
            for (int ci = 0; ci < 2; ++ci) {
                int c = cc + ci * 4;
                const float* p = v + (size_t)(kb + key) * D_HEAD + c * 8;
                float4 x = *(const float4*)p;
                float4 y = *(const float4*)(p + 4);
                float vals[8] = {x.x, x.y, x.z, x.w, y.x, y.y, y.z, y.w};
#pragma unroll
                for (int jj = 0; jj < 8; ++jj)
                    vs[buf][swz(c * 8 + jj, key)] = f2bf(vals[jj]);
            }
        }
    };

    stage(0, 0);

    for (int j = 0; j <= qb; ++j) {
        const int cur = j & 1;
        __syncthreads();                 // drains prefetch DMA (vmcnt) + guards reuse
        if (j < qb) stage(j + 1, 1 - cur);

        // ---- S = Q K^T
        f32x4 sf[4];
#pragma unroll
        for (int nt = 0; nt < 4; ++nt) sf[nt] = (f32x4){0.f, 0.f, 0.f, 0.f};
#pragma unroll
        for (int kt2 = 0; kt2 < 2; ++kt2) {
#pragma unroll
            for (int nt = 0; nt < 4; ++nt) {
                int key = nt * 16 + col;
                s16x8 bf = *(const s16x8*)&ks[cur][swz(key, (4 * kt2 + quad) * 8)];
                sf[nt] = __builtin_amdgcn_mfma_f32_16x16x32_bf16(qa[kt2], bf, sf[nt], 0, 0, 0);
            }
        }

        // ---- scale (+ causal mask on diagonal tile), exp2, P -> LDS
        if (j == qb) {
#pragma unroll
            for (int nt = 0; nt < 4; ++nt)
#pragma unroll
                for (int r = 0; r < 4; ++r) {
                    int keyl = nt * 16 + col;
                    int qrl  = w * 16 + quad * 4 + r;
                    sf[nt][r] = (keyl > qrl) ? -__builtin_inff() : sf[nt][r] * SCLOG2E;
                }
        } else {
#pragma unroll
            for (int nt = 0; nt < 4; ++nt)
#pragma unroll
                for (int r = 0; r < 4; ++r) sf[nt][r] *= SCLOG2E;
        }
#pragma unroll
        for (int nt = 0; nt < 4; ++nt)
#pragma unroll
            for (int r = 0; r < 4; ++r) {
                int qrl = quad * 4 + r;
                int key = nt * 16 + col;
                ps[w][swz(qrl, key)] = f2bf_hu(exp2f(sf[nt][r]));
            }
        // per-wave LDS region; in-wave DS ordering — no barrier needed

        // ---- O += P V ; l += P * ones  (row sums free via MFMA)
#pragma unroll
        for (int kt2 = 0; kt2 < 2; ++kt2) {
            s16x8 af = *(const s16x8*)&ps[w][swz(col, (4 * kt2 + quad) * 8)];
            lf = __builtin_amdgcn_mfma_f32_16x16x32_bf16(af, ones, lf, 0, 0, 0);
#pragma unroll
            for (int nt = 0; nt < 4; ++nt) {
                int d = nt * 16 + col;
                s16x8 bf = *(const s16x8*)&vs[cur][swz(d, (4 * kt2 + quad) * 8)];
                oacc[nt] = __builtin_amdgcn_mfma_f32_16x16x32_bf16(af, bf, oacc[nt], 0, 0, 0);
            }
        }
    }

    // ---- epilogue
#pragma unroll
    for (int r = 0; r < 4; ++r) {
        float inv = 1.f / lf[r];
        int row = qb * 64 + w * 16 + quad * 4 + r;
        float* po = o + (size_t)row * D_HEAD;
#pragma unroll
        for (int nt = 0; nt < 4; ++nt) po[nt * 16 + col] = oacc[nt][r] * inv;
    }
}

extern "C" void kernel_launch(void* const* d_in, const int* in_sizes, int n_in,
                              void* d_out, int out_size, void* d_ws, size_t ws_size,
                              hipStream_t stream) {
    const float* q = (const float*)d_in[0];
    const float* k = (const float*)d_in[1];
    const float* v = (const float*)d_in[2];
    float* out = (float*)d_out;

    const size_t kv_elems = (size_t)NBH * QBLK * TILE_E;   // 8M elems = 16 MB each
    if (ws_size >= 2 * kv_elems * sizeof(unsigned short)) {
        unsigned short* Kw = (unsigned short*)d_ws;
        unsigned short* Vw = Kw + kv_elems;
        preconv_kernel<<<dim3(NBH * QBLK), dim3(256), 0, stream>>>(k, v, Kw, Vw);
        fattn_kernel<true><<<dim3(NBH * QBLK), dim3(256), 0, stream>>>(q, k, v, out, Kw, Vw);
    } else {
        fattn_kernel<false><<<dim3(NBH * QBLK), dim3(256), 0, stream>>>(q, k, v, out, nullptr, nullptr);
    }
}

// Round 5
// 191.715 us; speedup vs baseline: 1.1174x; 1.1174x over previous
//
#include <hip/hip_runtime.h>

// Causal flash attention, B=4 H=16 S=2048 D=64, fp32 in/out, bf16 MFMA.
// R4: 32x32x16 MFMA, swapped QK^T (S^T = K x Q so q = lane&31) -> softmax fully
// in registers: scale*log2e folded into Q, raw v_exp, v_cvt_pk_bf16_f32 pairs,
// v_permlane32_swap to build PV A-frags. No P->LDS round-trip, no ones-MFMA
// (row sums via register tree + shfl_xor 32). QBLK=128 q-rows/block, 4 waves,
// LDS 33KB -> 4 blocks/CU. Preconv: K path direct global->global (no LDS).
// Kept: bf16 tile images in d_ws + global_load_lds staging, chunk-rotation
// swizzle (0 conflicts), XCD-affinity decode, heavy-first.

#define S_LEN 2048
#define D_HEAD 64
#define NBH 64      // B*H
#define KTILES 32   // S / 64 (64-key tiles)
#define QROWS 128   // q rows per block
#define NQB 16      // S / QROWS
#define TILE_E 4096 // 64x64 elements per tile image

typedef float f32x4 __attribute__((ext_vector_type(4)));
typedef float f32x16 __attribute__((ext_vector_type(16)));
typedef short s16x8 __attribute__((ext_vector_type(8)));
typedef unsigned int u32;
typedef u32 u32x4 __attribute__((ext_vector_type(4)));

#define SCLOG2E (0.125f * 1.44269504088896340736f)  // 1/sqrt(D) * log2(e)

__device__ __forceinline__ unsigned short f2bf(float x) {  // RNE
    union { float f; unsigned int u; } v; v.f = x;
    unsigned int u = v.u + 0x7FFFu + ((v.u >> 16) & 1u);
    return (unsigned short)(u >> 16);
}

// chunk-rotation swizzle (R1-verified: 0 bank conflicts)
__device__ __forceinline__ int swz(int row, int col) {
    return row * 64 + ((((col >> 3) + row) & 7) << 3) + (col & 7);
}

// async global->LDS, 16B per lane; lds dst must be wave-uniform base (lane*16 auto)
__device__ __forceinline__ void g2l(const unsigned short* g, unsigned short* l) {
    __builtin_amdgcn_global_load_lds(
        (const __attribute__((address_space(1))) void*)g,
        (__attribute__((address_space(3))) void*)l, 16, 0, 0);
}

// ---------- pre-pass: fp32 K,V -> bf16 swizzled tile images in workspace ----
__global__ __launch_bounds__(256)
void preconv_kernel(const float* __restrict__ K, const float* __restrict__ V,
                    unsigned short* __restrict__ Kw, unsigned short* __restrict__ Vw)
{
    __shared__ __align__(16) unsigned short vt[TILE_E];
    const int bh = blockIdx.x & (NBH - 1);
    const int j  = blockIdx.x >> 6;
    const float* k = K + (size_t)bh * (S_LEN * D_HEAD) + (size_t)j * 64 * D_HEAD;
    const float* v = V + (size_t)bh * (S_LEN * D_HEAD) + (size_t)j * 64 * D_HEAD;
    const int t = threadIdx.x;
    const size_t tb = (size_t)(bh * KTILES + j) * TILE_E;

    // K tile: row-major [key][d], swizzled, direct global->global (swz stays
    // within each row's 128B line -> stores remain fully coalesced)
#pragma unroll
    for (int i = 0; i < 2; ++i) {
        int chunk = t + 256 * i;
        int row = chunk >> 3, c = chunk & 7;
        const float* p = k + (size_t)row * D_HEAD + c * 8;
        float4 x = *(const float4*)p;
        float4 y = *(const float4*)(p + 4);
        s16x8 f;
        f[0] = (short)f2bf(x.x); f[1] = (short)f2bf(x.y);
        f[2] = (short)f2bf(x.z); f[3] = (short)f2bf(x.w);
        f[4] = (short)f2bf(y.x); f[5] = (short)f2bf(y.y);
        f[6] = (short)f2bf(y.z); f[7] = (short)f2bf(y.w);
        *(s16x8*)&Kw[tb + swz(row, c * 8)] = f;
    }
    // V tile: transposed [d][key], swizzled, via LDS
    {
        int key = t & 63, cc = t >> 6;
#pragma unroll
        for (int ci = 0; ci < 2; ++ci) {
            int c = cc + ci * 4;
            const float* p = v + (size_t)key * D_HEAD + c * 8;
            float4 x = *(const float4*)p;
            float4 y = *(const float4*)(p + 4);
            float vals[8] = {x.x, x.y, x.z, x.w, y.x, y.y, y.z, y.w};
#pragma unroll
            for (int jj = 0; jj < 8; ++jj)
                vt[swz(c * 8 + jj, key)] = f2bf(vals[jj]);
        }
    }
    __syncthreads();
#pragma unroll
    for (int i = 0; i < 2; ++i) {
        int idx = (t + 256 * i) * 8;
        *(s16x8*)&Vw[tb + idx] = *(const s16x8*)&vt[idx];
    }
}

// ---------------------------- main kernel -----------------------------------
template <bool PRE>
__global__ __launch_bounds__(256, 4)
void fattn_kernel(const float* __restrict__ Qg, const float* __restrict__ Kg,
                  const float* __restrict__ Vg, float* __restrict__ Og,
                  const unsigned short* __restrict__ Kw,
                  const unsigned short* __restrict__ Vw)
{
    __shared__ __align__(16) unsigned short ks[2][TILE_E];
    __shared__ __align__(16) unsigned short vs[2][TILE_E];
    __shared__ float lds_l[4][32];

    // XCD-affinity decode: bx&7 == XCD (grid 1024, 1024%8==0). 8 bh per XCD ->
    // KV image working set 8 x 512KB = 4 MiB = per-XCD L2. Heavy qb first.
    const int bx   = blockIdx.x;
    const int xcd  = bx & 7;
    const int slot = bx >> 3;                    // 0..127 per XCD
    const int bh   = xcd + ((slot & 7) << 3);
    const int qb   = (NQB - 1) - (slot >> 3);    // 0..15, heavy first
    const size_t base = (size_t)bh * (S_LEN * D_HEAD);
    const float* q = Qg + base;
    const float* k = Kg + base;
    const float* v = Vg + base;
    float*       o = Og + base;

    const int t    = threadIdx.x;
    const int w    = t >> 6;
    const int lane = t & 63;
    const int qc   = lane & 31;     // this lane's q column (32x32 C layout)
    const int hi   = lane >> 5;

    const int qseq = qb * QROWS + w * 32 + qc;   // this lane's q row (absolute)

    // Q B-frags for swapped QK^T: B[k=d][col=q], lane holds q=qc,
    // d = kt*16 + hi*8 + j. scale*log2(e) folded in here (frees a mul/elem).
    s16x8 qa[4];
#pragma unroll
    for (int kt = 0; kt < 4; ++kt) {
        const float* p = q + (size_t)qseq * D_HEAD + kt * 16 + hi * 8;
        float4 x = *(const float4*)p;
        float4 y = *(const float4*)(p + 4);
        s16x8 f;
        f[0] = (short)f2bf(x.x * SCLOG2E); f[1] = (short)f2bf(x.y * SCLOG2E);
        f[2] = (short)f2bf(x.z * SCLOG2E); f[3] = (short)f2bf(x.w * SCLOG2E);
        f[4] = (short)f2bf(y.x * SCLOG2E); f[5] = (short)f2bf(y.y * SCLOG2E);
        f[6] = (short)f2bf(y.z * SCLOG2E); f[7] = (short)f2bf(y.w * SCLOG2E);
        qa[kt] = f;
    }

    f32x16 o0 = {0,0,0,0,0,0,0,0,0,0,0,0,0,0,0,0};
    f32x16 o1 = {0,0,0,0,0,0,0,0,0,0,0,0,0,0,0,0};
    float l = 0.f;

    auto stage = [&](int jt, int buf) {
        if constexpr (PRE) {
            const size_t tb = (size_t)(bh * KTILES + jt) * TILE_E;
#pragma unroll
            for (int i = 0; i < 2; ++i) {
                int c = w * 2 + i;             // 8 chunks of 512 elem (1 KiB)
                g2l(Kw + tb + c * 512 + lane * 8, &ks[buf][c * 512]);
                g2l(Vw + tb + c * 512 + lane * 8, &vs[buf][c * 512]);
            }
        } else {
            const int kb = jt * 64;
#pragma unroll
            for (int i = 0; i < 2; ++i) {
                int chunk = t + 256 * i;
                int row = chunk >> 3, c = chunk & 7;
                const float* p = k + (size_t)(kb + row) * D_HEAD + c * 8;
                float4 x = *(const float4*)p;
                float4 y = *(const float4*)(p + 4);
                s16x8 f;
                f[0] = (short)f2bf(x.x); f[1] = (short)f2bf(x.y);
                f[2] = (short)f2bf(x.z); f[3] = (short)f2bf(x.w);
                f[4] = (short)f2bf(y.x); f[5] = (short)f2bf(y.y);
                f[6] = (short)f2bf(y.z); f[7] = (short)f2bf(y.w);
                *(s16x8*)&ks[buf][swz(row, c * 8)] = f;
            }
            int key = t & 63, cc = t >> 6;
#pragma unroll
            for (int ci = 0; ci < 2; ++ci) {
                int c = cc + ci * 4;
                const float* p = v + (size_t)(kb + key) * D_HEAD + c * 8;
                float4 x = *(const float4*)p;
                float4 y = *(const float4*)(p + 4);
                float vals[8] = {x.x, x.y, x.z, x.w, y.x, y.y, y.z, y.w};
#pragma unroll
                for (int jj = 0; jj < 8; ++jj)
                    vs[buf][swz(c * 8 + jj, key)] = f2bf(vals[jj]);
            }
        }
    };

    const int NT = 2 * qb + 2;       // 64-key tiles this block needs
    stage(0, 0);

    for (int j = 0; j < NT; ++j) {
        const int cur = j & 1;
        __syncthreads();             // drains prefetch DMA (vmcnt) + guards reuse
        if (j + 1 < NT) stage(j + 1, 1 - cur);

        // wave-uniform: skip tiles fully above the diagonal for this wave's q
        if (j * 64 > qb * QROWS + w * 32 + 31) continue;
        const bool domask = (j * 64 + 63 > qb * QROWS + w * 32);

#pragma unroll
        for (int kb = 0; kb < 2; ++kb) {
            // ---- S^T = K Q (32x32): col = q = qc, row = key via reg pattern
            f32x16 sf = {0,0,0,0,0,0,0,0,0,0,0,0,0,0,0,0};
#pragma unroll
            for (int kt = 0; kt < 4; ++kt) {
                s16x8 ka = *(const s16x8*)&ks[cur][swz(kb * 32 + qc, kt * 16 + hi * 8)];
                sf = __builtin_amdgcn_mfma_f32_32x32x16_bf16(ka, qa[kt], sf, 0, 0, 0);
            }

            // ---- mask + exp2 (scores already in log2 domain via Q pre-scale)
            if (domask) {
#pragma unroll
                for (int r = 0; r < 16; ++r) {
                    int key = j * 64 + kb * 32 + (r & 3) + 8 * (r >> 2) + 4 * hi;
                    sf[r] = (key > qseq) ? -__builtin_inff() : sf[r];
                }
            }
#pragma unroll
            for (int r = 0; r < 16; ++r) sf[r] = __builtin_amdgcn_exp2f(sf[r]);

            // ---- row-sum tree (16 adds, depth 4; partner half added at end)
            {
                float a0 = sf[0] + sf[1],   a1 = sf[2] + sf[3];
                float a2 = sf[4] + sf[5],   a3 = sf[6] + sf[7];
                float a4 = sf[8] + sf[9],   a5 = sf[10] + sf[11];
                float a6 = sf[12] + sf[13], a7 = sf[14] + sf[15];
                float b0 = a0 + a1, b1 = a2 + a3, b2 = a4 + a5, b3 = a6 + a7;
                l += (b0 + b1) + (b2 + b3);
            }

            // ---- P(f32) -> bf16 pairs, then permlane32_swap builds A-frags.
            // reg r holds key (r&3)+8*(r>>2)+4*hi, so c[i]=pack(sf[2i],sf[2i+1]):
            //  hi=0: c0=[0,1] c1=[2,3] c2=[8,9]  c3=[10,11] c4..c7 = +16
            //  hi=1: c0=[4,5] c1=[6,7] c2=[12,13] c3=[14,15] ...
            // swap(c0,c2),(c1,c3): frag m=0 = keys (8*hi..8*hi+7) of [0,15]. ✓
            u32 c[8];
#pragma unroll
            for (int r = 0; r < 8; ++r)
                asm("v_cvt_pk_bf16_f32 %0, %1, %2"
                    : "=v"(c[r]) : "v"(sf[2 * r]), "v"(sf[2 * r + 1]));
            asm("v_permlane32_swap_b32 %0, %1" : "+v"(c[0]), "+v"(c[2]));
            asm("v_permlane32_swap_b32 %0, %1" : "+v"(c[1]), "+v"(c[3]));
            asm("v_permlane32_swap_b32 %0, %1" : "+v"(c[4]), "+v"(c[6]));
            asm("v_permlane32_swap_b32 %0, %1" : "+v"(c[5]), "+v"(c[7]));
            u32x4 t0 = {c[0], c[1], c[2], c[3]};
            u32x4 t1 = {c[4], c[5], c[6], c[7]};
            s16x8 pa0 = __builtin_bit_cast(s16x8, t0);
            s16x8 pa1 = __builtin_bit_cast(s16x8, t1);

            // ---- O += P V (B-frag from V^T image: col=d=qc(+32), k=keys)
#pragma unroll
            for (int m = 0; m < 2; ++m) {
                s16x8 pa = m ? pa1 : pa0;
                int key0 = kb * 32 + m * 16 + hi * 8;
                s16x8 vb0 = *(const s16x8*)&vs[cur][swz(qc, key0)];
                o0 = __builtin_amdgcn_mfma_f32_32x32x16_bf16(pa, vb0, o0, 0, 0, 0);
                s16x8 vb1 = *(const s16x8*)&vs[cur][swz(32 + qc, key0)];
                o1 = __builtin_amdgcn_mfma_f32_32x32x16_bf16(pa, vb1, o1, 0, 0, 0);
            }
        }
    }

    // ---- epilogue: combine partner-half sums, broadcast 1/l via tiny LDS
    l += __shfl_xor(l, 32);
    if (hi == 0) lds_l[w][qc] = l;   // in-wave DS ordering; no barrier needed
#pragma unroll
    for (int r = 0; r < 16; ++r) {
        int rowp = (r & 3) + 8 * (r >> 2) + 4 * hi;          // q row in [0,31]
        float inv = 1.f / lds_l[w][rowp];
        int row_g = qb * QROWS + w * 32 + rowp;
        float* po = o + (size_t)row_g * D_HEAD;
        po[qc]      = o0[r] * inv;
        po[32 + qc] = o1[r] * inv;
    }
}

extern "C" void kernel_launch(void* const* d_in, const int* in_sizes, int n_in,
                              void* d_out, int out_size, void* d_ws, size_t ws_size,
                              hipStream_t stream) {
    const float* q = (const float*)d_in[0];
    const float* k = (const float*)d_in[1];
    const float* v = (const float*)d_in[2];
    float* out = (float*)d_out;

    const size_t kv_elems = (size_t)NBH * KTILES * TILE_E;   // 8M elems = 16 MB each
    if (ws_size >= 2 * kv_elems * sizeof(unsigned short)) {
        unsigned short* Kw = (unsigned short*)d_ws;
        unsigned short* Vw = Kw + kv_elems;
        preconv_kernel<<<dim3(NBH * KTILES), dim3(256), 0, stream>>>(k, v, Kw, Vw);
        fattn_kernel<true><<<dim3(NBH * NQB), dim3(256), 0, stream>>>(q, k, v, out, Kw, Vw);
    } else {
        fattn_kernel<false><<<dim3(NBH * NQB), dim3(256), 0, stream>>>(q, k, v, out, nullptr, nullptr);
    }
}